// Round 1
// baseline (572.952 us; speedup 1.0000x reference)
//
#include <hip/hip_runtime.h>
#include <math.h>

#define EPS 1e-8f

// Native clang vector type so __builtin_nontemporal_{load,store} accepts it.
typedef float f4 __attribute__((ext_vector_type(4)));

__device__ __forceinline__ float fuse1(float xv, float yv,
                                       float w0, float w1, float w2,
                                       float w3, float w4, float w5) {
    const float ax = fabsf(xv);
    const float ay = fabsf(yv);
    const float INV_2PI = 0.15915494309189535f;
    // native v_sin_f32 takes revolutions; |x|<~6 rad -> <1 rev, in range
    const float sy = __builtin_amdgcn_sinf(yv * INV_2PI);
    const float sx = __builtin_amdgcn_sinf(xv * INV_2PI);
    float r = w0 * (xv + yv);
    r = fmaf(w1, xv * yv, r);
    r = fmaf(w2 * xv, __builtin_amdgcn_rcpf(ay + EPS), r);
    r = fmaf(w3 * yv, __builtin_amdgcn_rcpf(ax + EPS), r);
    r = fmaf(w4 * xv, sy, r);
    r = fmaf(w5 * yv, sx, r);
    return r;
}

__global__ __launch_bounds__(256) void fused_op_kernel(
    const float* __restrict__ x, const float* __restrict__ y,
    const float* __restrict__ param, float* __restrict__ out, long long n)
{
    // ---- per-block recompute of w[6] = sum_j softmax(param, axis=0)[:, j] ----
    __shared__ float s_w[6];
    if (threadIdx.x < 6) s_w[threadIdx.x] = 0.0f;
    __syncthreads();
    if (threadIdx.x < 16) {
        const int j = threadIdx.x;
        float e[6];
        float sum = 0.0f;
#pragma unroll
        for (int i = 0; i < 6; ++i) {
            e[i] = __expf(param[i * 16 + j]);   // param in [0,1): no overflow, max-sub unneeded
            sum += e[i];
        }
        const float inv = 1.0f / sum;
#pragma unroll
        for (int i = 0; i < 6; ++i) atomicAdd(&s_w[i], e[i] * inv);
    }
    __syncthreads();
    const float w0 = s_w[0], w1 = s_w[1], w2 = s_w[2];
    const float w3 = s_w[3], w4 = s_w[4], w5 = s_w[5];

    // ---- streaming elementwise main loop, float4 ----
    const long long n4 = n >> 2;
    const f4* __restrict__ x4 = (const f4*)x;
    const f4* __restrict__ y4 = (const f4*)y;
    f4* __restrict__ o4 = (f4*)out;

    const long long stride = (long long)gridDim.x * blockDim.x;
    for (long long i = (long long)blockIdx.x * blockDim.x + threadIdx.x;
         i < n4; i += stride) {
        const f4 a = __builtin_nontemporal_load(&x4[i]);
        const f4 b = __builtin_nontemporal_load(&y4[i]);
        f4 r;
#pragma unroll
        for (int c = 0; c < 4; ++c)
            r[c] = fuse1(a[c], b[c], w0, w1, w2, w3, w4, w5);
        __builtin_nontemporal_store(r, &o4[i]);
    }

    // ---- scalar tail (n not divisible by 4) ----
    const long long tail_start = n4 << 2;
    for (long long i = tail_start + (long long)blockIdx.x * blockDim.x + threadIdx.x;
         i < n; i += stride) {
        out[i] = fuse1(x[i], y[i], w0, w1, w2, w3, w4, w5);
    }
}

extern "C" void kernel_launch(void* const* d_in, const int* in_sizes, int n_in,
                              void* d_out, int out_size, void* d_ws, size_t ws_size,
                              hipStream_t stream) {
    const float* x = (const float*)d_in[0];
    const float* y = (const float*)d_in[1];
    const float* param = (const float*)d_in[2];
    float* out = (float*)d_out;
    const long long n = (long long)in_sizes[0];

    const int block = 256;
    const int grid = 8192;  // grid-stride: 2.1M threads, ~8 float4 iters each
    fused_op_kernel<<<grid, block, 0, stream>>>(x, y, param, out, n);
}